// Round 12
// baseline (837.175 us; speedup 1.0000x reference)
//
#include <hip/hip_runtime.h>
#include <hip/hip_fp16.h>
#include <stdint.h>

#define VV 32000
#define HH 256
#define BB 32
#define TT 128
#define VH 32256  // V + H

typedef _Float16 f16;
typedef _Float16 f16x2 __attribute__((ext_vector_type(2)));
typedef _Float16 f16x8 __attribute__((ext_vector_type(8)));
typedef float f32x4 __attribute__((ext_vector_type(4)));

static __device__ __forceinline__ float dot2f(uint32_t w, uint32_t h, float acc){
  f16x2 a = __builtin_bit_cast(f16x2, w);
  f16x2 b = __builtin_bit_cast(f16x2, h);
#if __has_builtin(__builtin_amdgcn_fdot2)
  return __builtin_amdgcn_fdot2(a, b, acc, false);
#else
  acc = fmaf((float)a[0], (float)b[0], acc);
  acc = fmaf((float)a[1], (float)b[1], acc);
  return acc;
#endif
}

// ---------------- gather: g[t*32+b][o] = W_gate[row][tok] + bias
__global__ void k_gather(const int* __restrict__ X,
                         const float* __restrict__ Wz, const float* __restrict__ bz,
                         const float* __restrict__ Wr, const float* __restrict__ br,
                         const float* __restrict__ Wh, const float* __restrict__ bh,
                         float* __restrict__ g_buf){
  int tb = blockIdx.x;              // t*32 + b
  int t = tb >> 5, b = tb & 31;
  int tok = X[b*TT + t];
  int o = threadIdx.x;              // 0..255
  g_buf[(size_t)tb*768 + o]       = Wz[(size_t)o*VH + tok] + bz[o];
  g_buf[(size_t)tb*768 + 256 + o] = Wr[(size_t)o*VH + tok] + br[o];
  g_buf[(size_t)tb*768 + 512 + o] = Wh[(size_t)o*VH + tok] + bh[o];
}

// ---------------- pack recurrent weights for 512-thread recurrence layout (round-8 champion)
// thread t: ko=t&7, no=t>>3 in [0,64)
// ol<8 -> o=no*8+ol (o<256: Wz row o; else Wr row o-256); ol in [8,12): Wh row no*4+(ol-8)
__global__ void k_pack(const float* __restrict__ Wz, const float* __restrict__ Wr,
                       const float* __restrict__ Wh, uint32_t* __restrict__ Wpack){
  int idx = blockIdx.x*256 + threadIdx.x;
  if (idx >= 512*192) return;
  int t = idx / 192, rem = idx - t*192;
  int ol = rem >> 4, p = rem & 15;
  int ko = t & 7, no = t >> 3;
  int k = ko*32 + p*2;
  const float* W; int row;
  if (ol < 8){ int o = no*8 + ol; if (o < 256){ W = Wz; row = o; } else { W = Wr; row = o - 256; } }
  else { W = Wh; row = no*4 + (ol - 8); }
  float a = W[(size_t)row*VH + VV + k];
  float c = W[(size_t)row*VH + VV + k + 1];
  f16x2 v; v[0] = (f16)a; v[1] = (f16)c;
  Wpack[idx] = __builtin_bit_cast(uint32_t, v);
}

// ---------------- recurrence: 32 blocks x 512 threads, waves_per_eu(2,2)  [round-8 champion]
__global__ __launch_bounds__(512)
__attribute__((amdgpu_waves_per_eu(2, 2)))
void k_recur(const float* __restrict__ H0,
             const uint32_t* __restrict__ Wpack,
             const float* __restrict__ g_buf,
             f16* __restrict__ Hn16,
             float* __restrict__ hf_out){
  __shared__ __align__(16) uint32_t hs16[128];   // Hs as f16 pairs
  __shared__ __align__(16) f16 rHs16[256];       // r*Hs as f16
  __shared__ float hs32[256];                    // Hs f32 (state of record)
  __shared__ float z_s[256];

  const int b = blockIdx.x;
  const int tid = threadIdx.x;
  const int ko = tid & 7, no = tid >> 3;   // no in [0,64)

  uint32_t w[12][16];
  {
    const uint4* src = (const uint4*)(Wpack + (size_t)tid*192);
    #pragma unroll
    for (int j=0;j<48;j++){
      uint4 v = src[j];
      int f = j*4;
      w[(f+0)>>4][(f+0)&15] = v.x;
      w[(f+1)>>4][(f+1)&15] = v.y;
      w[(f+2)>>4][(f+2)&15] = v.z;
      w[(f+3)>>4][(f+3)&15] = v.w;
    }
  }

  if (tid < 256) hs32[tid] = H0[b*HH + tid];
  __syncthreads();
  if (tid < 128){
    f16x2 v; v[0] = (f16)hs32[2*tid]; v[1] = (f16)hs32[2*tid+1];
    hs16[tid] = __builtin_bit_cast(uint32_t, v);
  }
  __syncthreads();

  const int gi1 = no*8 + ko;
  const int gi2 = 512 + no*4 + (ko & 3);
  float g1 = g_buf[(size_t)b*768 + gi1];
  float g2 = g_buf[(size_t)b*768 + gi2];
  float g1n = 0.f, g2n = 0.f;

  for (int t = 0; t < TT; t++){
    if (t < TT-1){
      const float* gn = g_buf + (size_t)((t+1)*BB + b)*768;
      g1n = gn[gi1];
      g2n = gn[gi2];
    }

    // ---- phase 1
    uint32_t hp[16];
    {
      const uint2* hsp = (const uint2*)hs16;
      #pragma unroll
      for (int j=0;j<8;j++){ uint2 v = hsp[ko*8 + j]; hp[2*j] = v.x; hp[2*j+1] = v.y; }
    }
    float acc[8];
    #pragma unroll
    for (int ol=0;ol<8;ol++) acc[ol] = 0.f;
    #pragma unroll
    for (int p=0;p<16;p++)
      #pragma unroll
      for (int ol=0;ol<8;ol++)
        acc[ol] = dot2f(w[ol][p], hp[p], acc[ol]);
    #pragma unroll
    for (int ol=0;ol<8;ol++){
      float v2 = acc[ol];
      v2 += __shfl_xor(v2, 1);
      v2 += __shfl_xor(v2, 2);
      v2 += __shfl_xor(v2, 4);
      acc[ol] = v2;
    }
    {
      float sel = acc[0];
      #pragma unroll
      for (int ol=1;ol<8;ol++) sel = (ko == ol) ? acc[ol] : sel;
      float pre = sel + g1;
      float s = 1.f / (1.f + __expf(-pre));
      int o = no*8 + ko;
      if (no < 32){
        z_s[o] = s;
      } else {
        int op = o - 256;
        rHs16[op] = (f16)(s * hs32[op]);
      }
    }
    __syncthreads();

    // ---- phase 2
    uint32_t rp[16];
    {
      const uint2* rpp = (const uint2*)rHs16;
      #pragma unroll
      for (int j=0;j<8;j++){ uint2 v = rpp[ko*8 + j]; rp[2*j] = v.x; rp[2*j+1] = v.y; }
    }
    float a2[4];
    #pragma unroll
    for (int oi=0;oi<4;oi++) a2[oi] = 0.f;
    #pragma unroll
    for (int p=0;p<16;p++)
      #pragma unroll
      for (int oi=0;oi<4;oi++)
        a2[oi] = dot2f(w[8+oi][p], rp[p], a2[oi]);
    #pragma unroll
    for (int oi=0;oi<4;oi++){
      float v2 = a2[oi];
      v2 += __shfl_xor(v2, 1);
      v2 += __shfl_xor(v2, 2);
      v2 += __shfl_xor(v2, 4);
      a2[oi] = v2;
    }
    if (ko < 4){
      float sel = a2[0];
      #pragma unroll
      for (int oi=1;oi<4;oi++) sel = (ko == oi) ? a2[oi] : sel;
      int o = no*4 + ko;
      float pre = sel + g2;
      float ax = fabsf(pre);
      float e = __expf(2.f*ax);
      float th = 1.f - 2.f/(e + 1.f);      // tanh(|x|), safe at inf
      th = copysignf(th, pre);
      float z = z_s[o];
      float hn = z*th + (1.f - z)*hs32[o];
      hs32[o] = hn;
      ((f16*)hs16)[o] = (f16)hn;
      Hn16[(size_t)(t*BB + b)*HH + o] = (f16)hn;
      if (t == TT-1) hf_out[b*HH + o] = hn;
    }
    g1 = g1n; g2 = g2n;
    __syncthreads();
  }
}

// ---------------- output GEMM: Y[4096][32000] = Hn16[4096][256] @ Wo^T (f16 MFMA) + bo
// LDS-bounce epilogue: 32-row chunks staged in a_lds, streamed as contiguous float4 rows
__global__ __launch_bounds__(256) void k_gemm(const f16* __restrict__ A, const float* __restrict__ Wo,
                                              const float* __restrict__ bo, float* __restrict__ Y){
  __shared__ __align__(16) f16 a_lds[128*128];
  __shared__ __align__(16) f16 b_lds[128*128];
  const int m0 = blockIdx.x * 128;   // m fastest -> consecutive blocks share Wo n-panel in L2
  const int n0 = blockIdx.y * 128;
  const int tid = threadIdx.x;
  const int lane = tid & 63, wave = tid >> 6;
  const int wm = wave >> 1, wn = wave & 1;

  f32x4 acc[4][4];
  {
    f32x4 z = {0.f, 0.f, 0.f, 0.f};
    #pragma unroll
    for (int i=0;i<4;i++)
      #pragma unroll
      for (int j=0;j<4;j++) acc[i][j] = z;
  }

  const int srow = tid >> 1, seg = tid & 1;
  #pragma unroll 1
  for (int kt=0; kt<2; kt++){
    const int k0 = kt*128;
    {
      const uint4* asrc = (const uint4*)(A + (size_t)(m0+srow)*256 + k0 + seg*64);
      #pragma unroll
      for (int j=0;j<8;j++){
        uint4 v = asrc[j];
        int byte = (srow*256 + seg*128 + j*16) ^ ((srow&7)<<4);
        *(uint4*)((char*)a_lds + byte) = v;
      }
      const float4* bsrc = (const float4*)(Wo + (size_t)(n0+srow)*256 + k0 + seg*64);
      #pragma unroll
      for (int j=0;j<8;j++){
        float4 f0 = bsrc[2*j], f1 = bsrc[2*j+1];
        f16x8 hv;
        hv[0]=(f16)f0.x; hv[1]=(f16)f0.y; hv[2]=(f16)f0.z; hv[3]=(f16)f0.w;
        hv[4]=(f16)f1.x; hv[5]=(f16)f1.y; hv[6]=(f16)f1.z; hv[7]=(f16)f1.w;
        int byte = (srow*256 + seg*128 + j*16) ^ ((srow&7)<<4);
        *(f16x8*)((char*)b_lds + byte) = hv;
      }
    }
    __syncthreads();
    #pragma unroll
    for (int kk=0; kk<4; kk++){
      const int kbyte = kk*64 + (lane>>4)*16;
      f16x8 af[4], bf[4];
      #pragma unroll
      for (int mi=0;mi<4;mi++){
        int row = wm*64 + mi*16 + (lane&15);
        int byte = (row*256 + kbyte) ^ ((row&7)<<4);
        af[mi] = *(const f16x8*)((const char*)a_lds + byte);
      }
      #pragma unroll
      for (int nj=0;nj<4;nj++){
        int nl = wn*64 + nj*16 + (lane&15);
        int byte = (nl*256 + kbyte) ^ ((nl&7)<<4);
        bf[nj] = *(const f16x8*)((const char*)b_lds + byte);
      }
      #pragma unroll
      for (int mi=0;mi<4;mi++)
        #pragma unroll
        for (int nj=0;nj<4;nj++)
          acc[mi][nj] = __builtin_amdgcn_mfma_f32_16x16x32_f16(af[mi], bf[nj], acc[mi][nj], 0, 0, 0);
    }
    __syncthreads();
  }

  // ---- LDS-bounce epilogue (reuses a_lds): 4 chunks of 32 rows x 128 cols
  float* lds_ep = (float*)a_lds;   // needs 32*132*4 = 16,896 B <= 32 KB
  #pragma unroll 1
  for (int c=0;c<4;c++){
    if (wm == (c>>1)){
      #pragma unroll
      for (int mi2=0;mi2<2;mi2++){
        int mi = (c&1)*2 + mi2;
        #pragma unroll
        for (int nj=0;nj<4;nj++){
          int col = wn*64 + nj*16 + (lane&15);
          #pragma unroll
          for (int r=0;r<4;r++){
            int lr = mi2*16 + (lane>>4)*4 + r;   // 0..31
            lds_ep[lr*132 + col] = acc[mi][nj][r];
          }
        }
      }
    }
    __syncthreads();
    #pragma unroll
    for (int i=0;i<4;i++){
      int idx = i*256 + tid;          // 0..1023
      int lr = idx >> 5;              // 0..31
      int q  = idx & 31;              // 0..31 (float4 index)
      float4 v = *(const float4*)(lds_ep + lr*132 + q*4);
      float4 bv = *(const float4*)(bo + n0 + q*4);
      v.x += bv.x; v.y += bv.y; v.z += bv.z; v.w += bv.w;
      *(float4*)(Y + (size_t)(m0 + c*32 + lr)*VV + n0 + q*4) = v;
    }
    __syncthreads();
  }
}

extern "C" void kernel_launch(void* const* d_in, const int* in_sizes, int n_in,
                              void* d_out, int out_size, void* d_ws, size_t ws_size,
                              hipStream_t stream){
  const int*   X  = (const int*)d_in[0];
  const float* H0 = (const float*)d_in[1];
  const float* Wz = (const float*)d_in[2];
  const float* bz = (const float*)d_in[3];
  const float* Wr = (const float*)d_in[4];
  const float* br = (const float*)d_in[5];
  const float* Wh = (const float*)d_in[6];
  const float* bh = (const float*)d_in[7];
  const float* Wo = (const float*)d_in[8];
  const float* bo = (const float*)d_in[9];
  float* out = (float*)d_out;

  char* ws = (char*)d_ws;
  float*    g_buf = (float*)ws;                               // 4096*768*4  = 12,582,912 B
  uint32_t* Wpack = (uint32_t*)(ws + 12582912);               // 512*192*4   =    393,216 B
  f16*      Hn16  = (f16*)(ws + 12582912 + 393216);           // 4096*256*2  =  2,097,152 B

  k_gather<<<4096, 256, 0, stream>>>(X, Wz, bz, Wr, br, Wh, bh, g_buf);
  k_pack<<<384, 256, 0, stream>>>(Wz, Wr, Wh, Wpack);
  k_recur<<<32, 512, 0, stream>>>(H0, Wpack, g_buf, Hn16, out + 131072000LL);
  k_gemm<<<dim3(32, 250), 256, 0, stream>>>(Hn16, Wo, bo, out);
}

// Round 13
// 689.656 us; speedup vs baseline: 1.2139x; 1.2139x over previous
//
#include <hip/hip_runtime.h>
#include <hip/hip_fp16.h>
#include <stdint.h>

#define VV 32000
#define HH 256
#define BB 32
#define TT 128
#define VH 32256  // V + H

typedef _Float16 f16;
typedef _Float16 f16x2 __attribute__((ext_vector_type(2)));
typedef _Float16 f16x8 __attribute__((ext_vector_type(8)));
typedef float f32x4 __attribute__((ext_vector_type(4)));

static __device__ __forceinline__ float dot2f(uint32_t w, uint32_t h, float acc){
  f16x2 a = __builtin_bit_cast(f16x2, w);
  f16x2 b = __builtin_bit_cast(f16x2, h);
#if __has_builtin(__builtin_amdgcn_fdot2)
  return __builtin_amdgcn_fdot2(a, b, acc, false);
#else
  acc = fmaf((float)a[0], (float)b[0], acc);
  acc = fmaf((float)a[1], (float)b[1], acc);
  return acc;
#endif
}

// ---------------- gather: g[t*32+b][o] = W_gate[row][tok] + bias
__global__ void k_gather(const int* __restrict__ X,
                         const float* __restrict__ Wz, const float* __restrict__ bz,
                         const float* __restrict__ Wr, const float* __restrict__ br,
                         const float* __restrict__ Wh, const float* __restrict__ bh,
                         float* __restrict__ g_buf){
  int tb = blockIdx.x;              // t*32 + b
  int t = tb >> 5, b = tb & 31;
  int tok = X[b*TT + t];
  int o = threadIdx.x;              // 0..255
  g_buf[(size_t)tb*768 + o]       = Wz[(size_t)o*VH + tok] + bz[o];
  g_buf[(size_t)tb*768 + 256 + o] = Wr[(size_t)o*VH + tok] + br[o];
  g_buf[(size_t)tb*768 + 512 + o] = Wh[(size_t)o*VH + tok] + bh[o];
}

// ---------------- pack recurrent weights (512-thread layout, round-8 mapping)
__global__ void k_pack(const float* __restrict__ Wz, const float* __restrict__ Wr,
                       const float* __restrict__ Wh, uint32_t* __restrict__ Wpack){
  int idx = blockIdx.x*256 + threadIdx.x;
  if (idx >= 512*192) return;
  int t = idx / 192, rem = idx - t*192;
  int ol = rem >> 4, p = rem & 15;
  int ko = t & 7, no = t >> 3;
  int k = ko*32 + p*2;
  const float* W; int row;
  if (ol < 8){ int o = no*8 + ol; if (o < 256){ W = Wz; row = o; } else { W = Wr; row = o - 256; } }
  else { W = Wh; row = no*4 + (ol - 8); }
  float a = W[(size_t)row*VH + VV + k];
  float c = W[(size_t)row*VH + VV + k + 1];
  f16x2 v; v[0] = (f16)a; v[1] = (f16)c;
  Wpack[idx] = __builtin_bit_cast(uint32_t, v);
}

// ---------------- Wo f32 -> f16 (once): kills staging cvts + halves panel bytes
__global__ void k_wo(const float* __restrict__ Wo, f16* __restrict__ Wof){
  int i = blockIdx.x*256 + threadIdx.x;      // 1,024,000 threads x 8 floats
  const float4* s = (const float4*)Wo + (size_t)i*2;
  float4 f0 = s[0], f1 = s[1];
  f16x8 h;
  h[0]=(f16)f0.x; h[1]=(f16)f0.y; h[2]=(f16)f0.z; h[3]=(f16)f0.w;
  h[4]=(f16)f1.x; h[5]=(f16)f1.y; h[6]=(f16)f1.z; h[7]=(f16)f1.w;
  *(f16x8*)(Wof + (size_t)i*8) = h;
}

// ==== AGPR pinning machinery: 192 weight dwords live in AGPRs across the t-loop ====
#define DECL16(P) uint32_t P##_0,P##_1,P##_2,P##_3,P##_4,P##_5,P##_6,P##_7, \
                           P##_8,P##_9,P##_10,P##_11,P##_12,P##_13,P##_14,P##_15;
#define LDQ(j,e0,e1,e2,e3) { uint4 v_ = src[j]; \
  asm("v_accvgpr_write_b32 %0, %1" : "=a"(e0) : "v"(v_.x)); \
  asm("v_accvgpr_write_b32 %0, %1" : "=a"(e1) : "v"(v_.y)); \
  asm("v_accvgpr_write_b32 %0, %1" : "=a"(e2) : "v"(v_.z)); \
  asm("v_accvgpr_write_b32 %0, %1" : "=a"(e3) : "v"(v_.w)); }
#define LDROW(r,P) LDQ(4*(r)+0,P##_0,P##_1,P##_2,P##_3)   LDQ(4*(r)+1,P##_4,P##_5,P##_6,P##_7) \
                   LDQ(4*(r)+2,P##_8,P##_9,P##_10,P##_11) LDQ(4*(r)+3,P##_12,P##_13,P##_14,P##_15)
// volatile: prevents hoisting/CSE of reads out of the t-loop (would rebuild VGPR pressure)
#define RD(a_) __extension__({ uint32_t t_; \
  asm volatile("v_accvgpr_read_b32 %0, %1" : "=v"(t_) : "a"(a_)); t_; })
#define DOTP1(p) \
  a0 = dot2f(RD(w0_##p), hp[p], a0);  a1 = dot2f(RD(w1_##p), hp[p], a1); \
  a2 = dot2f(RD(w2_##p), hp[p], a2);  a3 = dot2f(RD(w3_##p), hp[p], a3); \
  a4 = dot2f(RD(w4_##p), hp[p], a4);  a5 = dot2f(RD(w5_##p), hp[p], a5); \
  a6 = dot2f(RD(w6_##p), hp[p], a6);  a7 = dot2f(RD(w7_##p), hp[p], a7);
#define DOTP2(p) \
  b0 = dot2f(RD(w8_##p),  rp[p], b0); b1 = dot2f(RD(w9_##p),  rp[p], b1); \
  b2 = dot2f(RD(w10_##p), rp[p], b2); b3 = dot2f(RD(w11_##p), rp[p], b3);
#define REDUCE(x) x += __shfl_xor(x,1); x += __shfl_xor(x,2); x += __shfl_xor(x,4);

// ---------------- recurrence: 32 blocks x 512 threads; weights in AGPRs (no L2 remat)
__global__ __launch_bounds__(512)
__attribute__((amdgpu_waves_per_eu(2, 2)))
void k_recur(const float* __restrict__ H0,
             const uint32_t* __restrict__ Wpack,
             const float* __restrict__ g_buf,
             f16* __restrict__ Hn16,
             float* __restrict__ hf_out){
  __shared__ __align__(16) uint32_t hs16[128];   // Hs as f16 pairs
  __shared__ __align__(16) f16 rHs16[256];       // r*Hs as f16
  __shared__ float hs32[256];                    // Hs f32 (state of record)
  __shared__ float z_s[256];

  const int b = blockIdx.x;
  const int tid = threadIdx.x;
  const int ko = tid & 7, no = tid >> 3;   // no in [0,64)

  DECL16(w0) DECL16(w1) DECL16(w2)  DECL16(w3)  DECL16(w4)  DECL16(w5)
  DECL16(w6) DECL16(w7) DECL16(w8)  DECL16(w9)  DECL16(w10) DECL16(w11)
  {
    const uint4* src = (const uint4*)(Wpack + (size_t)tid*192);
    LDROW(0,w0) LDROW(1,w1) LDROW(2,w2)   LDROW(3,w3)  LDROW(4,w4)  LDROW(5,w5)
    LDROW(6,w6) LDROW(7,w7) LDROW(8,w8)   LDROW(9,w9)  LDROW(10,w10) LDROW(11,w11)
  }

  if (tid < 256) hs32[tid] = H0[b*HH + tid];
  __syncthreads();
  if (tid < 128){
    f16x2 v; v[0] = (f16)hs32[2*tid]; v[1] = (f16)hs32[2*tid+1];
    hs16[tid] = __builtin_bit_cast(uint32_t, v);
  }
  __syncthreads();

  const int gi1 = no*8 + ko;
  const int gi2 = 512 + no*4 + (ko & 3);
  float g1 = g_buf[(size_t)b*768 + gi1];
  float g2 = g_buf[(size_t)b*768 + gi2];
  float g1n = 0.f, g2n = 0.f;

  for (int t = 0; t < TT; t++){
    if (t < TT-1){
      const float* gn = g_buf + (size_t)((t+1)*BB + b)*768;
      g1n = gn[gi1];
      g2n = gn[gi2];
    }

    // ---- phase 1: z (no<32) and r (no>=32), 8 outputs per group
    uint32_t hp[16];
    {
      const uint2* hsp = (const uint2*)hs16;
      #pragma unroll
      for (int j=0;j<8;j++){ uint2 v = hsp[ko*8 + j]; hp[2*j] = v.x; hp[2*j+1] = v.y; }
    }
    float a0=0.f,a1=0.f,a2=0.f,a3=0.f,a4=0.f,a5=0.f,a6=0.f,a7=0.f;
    DOTP1(0)  DOTP1(1)  DOTP1(2)  DOTP1(3)  DOTP1(4)  DOTP1(5)  DOTP1(6)  DOTP1(7)
    DOTP1(8)  DOTP1(9)  DOTP1(10) DOTP1(11) DOTP1(12) DOTP1(13) DOTP1(14) DOTP1(15)
    REDUCE(a0) REDUCE(a1) REDUCE(a2) REDUCE(a3) REDUCE(a4) REDUCE(a5) REDUCE(a6) REDUCE(a7)
    {
      float sel = a0;
      sel = (ko==1)?a1:sel; sel = (ko==2)?a2:sel; sel = (ko==3)?a3:sel;
      sel = (ko==4)?a4:sel; sel = (ko==5)?a5:sel; sel = (ko==6)?a6:sel; sel = (ko==7)?a7:sel;
      float pre = sel + g1;
      float s = 1.f / (1.f + __expf(-pre));
      int o = no*8 + ko;
      if (no < 32){
        z_s[o] = s;
      } else {
        int op = o - 256;
        rHs16[op] = (f16)(s * hs32[op]);
      }
    }
    __syncthreads();

    // ---- phase 2: h~ = tanh(gh + (r*Hs)@Wh^T), Hn = z*h~ + (1-z)*Hs
    uint32_t rp[16];
    {
      const uint2* rpp = (const uint2*)rHs16;
      #pragma unroll
      for (int j=0;j<8;j++){ uint2 v = rpp[ko*8 + j]; rp[2*j] = v.x; rp[2*j+1] = v.y; }
    }
    float b0=0.f,b1=0.f,b2=0.f,b3=0.f;
    DOTP2(0)  DOTP2(1)  DOTP2(2)  DOTP2(3)  DOTP2(4)  DOTP2(5)  DOTP2(6)  DOTP2(7)
    DOTP2(8)  DOTP2(9)  DOTP2(10) DOTP2(11) DOTP2(12) DOTP2(13) DOTP2(14) DOTP2(15)
    REDUCE(b0) REDUCE(b1) REDUCE(b2) REDUCE(b3)
    if (ko < 4){
      float sel = b0;
      sel = (ko==1)?b1:sel; sel = (ko==2)?b2:sel; sel = (ko==3)?b3:sel;
      int o = no*4 + ko;
      float pre = sel + g2;
      float ax = fabsf(pre);
      float e = __expf(2.f*ax);
      float th = 1.f - 2.f/(e + 1.f);      // tanh(|x|), safe at inf
      th = copysignf(th, pre);
      float z = z_s[o];
      float hn = z*th + (1.f - z)*hs32[o];
      hs32[o] = hn;
      ((f16*)hs16)[o] = (f16)hn;
      Hn16[(size_t)(t*BB + b)*HH + o] = (f16)hn;
      if (t == TT-1) hf_out[b*HH + o] = hn;
    }
    g1 = g1n; g2 = g2n;
    __syncthreads();
  }
}

// ---------------- output GEMM: Y = Hn16 @ Wof^T + bo; direct-store epilogue (proven),
// f16 B staging, XCD-chunked bijective swizzle (each XCD owns a contiguous n-panel range)
__global__ __launch_bounds__(256) void k_gemm(const f16* __restrict__ A, const f16* __restrict__ Wof,
                                              const float* __restrict__ bo, float* __restrict__ Y){
  __shared__ __align__(16) f16 a_lds[128*128];
  __shared__ __align__(16) f16 b_lds[128*128];
  const int wg = (blockIdx.x & 7)*1000 + (blockIdx.x >> 3);   // 8000 = 8 x 1000, bijective
  const int m0 = (wg & 31) * 128;      // m fastest within an XCD chunk -> n-panel reuse in L2
  const int n0 = (wg >> 5) * 128;
  const int tid = threadIdx.x;
  const int lane = tid & 63, wave = tid >> 6;
  const int wm = wave >> 1, wn = wave & 1;

  f32x4 acc[4][4];
  {
    f32x4 z = {0.f, 0.f, 0.f, 0.f};
    #pragma unroll
    for (int i=0;i<4;i++)
      #pragma unroll
      for (int j=0;j<4;j++) acc[i][j] = z;
  }

  const int srow = tid >> 1, seg = tid & 1;
  #pragma unroll 1
  for (int kt=0; kt<2; kt++){
    const int k0 = kt*128;
    {
      const uint4* asrc = (const uint4*)(A + (size_t)(m0+srow)*256 + k0 + seg*64);
      const uint4* bsrc = (const uint4*)(Wof + (size_t)(n0+srow)*256 + k0 + seg*64);
      #pragma unroll
      for (int j=0;j<8;j++){
        uint4 av = asrc[j];
        int byte = (srow*256 + seg*128 + j*16) ^ ((srow&7)<<4);
        *(uint4*)((char*)a_lds + byte) = av;
        uint4 bv = bsrc[j];
        *(uint4*)((char*)b_lds + byte) = bv;
      }
    }
    __syncthreads();
    #pragma unroll
    for (int kk=0; kk<4; kk++){
      const int kbyte = kk*64 + (lane>>4)*16;
      f16x8 af[4], bf[4];
      #pragma unroll
      for (int mi=0;mi<4;mi++){
        int row = wm*64 + mi*16 + (lane&15);
        int byte = (row*256 + kbyte) ^ ((row&7)<<4);
        af[mi] = *(const f16x8*)((const char*)a_lds + byte);
      }
      #pragma unroll
      for (int nj=0;nj<4;nj++){
        int nl = wn*64 + nj*16 + (lane&15);
        int byte = (nl*256 + kbyte) ^ ((nl&7)<<4);
        bf[nj] = *(const f16x8*)((const char*)b_lds + byte);
      }
      #pragma unroll
      for (int mi=0;mi<4;mi++)
        #pragma unroll
        for (int nj=0;nj<4;nj++)
          acc[mi][nj] = __builtin_amdgcn_mfma_f32_16x16x32_f16(af[mi], bf[nj], acc[mi][nj], 0, 0, 0);
    }
    __syncthreads();
  }
  // direct-store epilogue: C/D map col = lane&15, row = (lane>>4)*4 + reg (64-B full lines)
  #pragma unroll
  for (int nj=0;nj<4;nj++){
    const int col = n0 + wn*64 + nj*16 + (lane & 15);
    const float bov = bo[col];
    #pragma unroll
    for (int mi=0;mi<4;mi++){
      const int rbase = m0 + wm*64 + mi*16 + (lane>>4)*4;
      #pragma unroll
      for (int r=0;r<4;r++){
        Y[(size_t)(rbase + r)*VV + col] = acc[mi][nj][r] + bov;
      }
    }
  }
}

extern "C" void kernel_launch(void* const* d_in, const int* in_sizes, int n_in,
                              void* d_out, int out_size, void* d_ws, size_t ws_size,
                              hipStream_t stream){
  const int*   X  = (const int*)d_in[0];
  const float* H0 = (const float*)d_in[1];
  const float* Wz = (const float*)d_in[2];
  const float* bz = (const float*)d_in[3];
  const float* Wr = (const float*)d_in[4];
  const float* br = (const float*)d_in[5];
  const float* Wh = (const float*)d_in[6];
  const float* bh = (const float*)d_in[7];
  const float* Wo = (const float*)d_in[8];
  const float* bo = (const float*)d_in[9];
  float* out = (float*)d_out;

  char* ws = (char*)d_ws;
  float*    g_buf = (float*)ws;                               // 12,582,912 B
  uint32_t* Wpack = (uint32_t*)(ws + 12582912);               //    393,216 B
  f16*      Hn16  = (f16*)(ws + 12582912 + 393216);           //  2,097,152 B
  f16*      Wof   = (f16*)(ws + 12582912 + 393216 + 2097152); // 16,384,000 B

  k_gather<<<4096, 256, 0, stream>>>(X, Wz, bz, Wr, br, Wh, bh, g_buf);
  k_pack<<<384, 256, 0, stream>>>(Wz, Wr, Wh, Wpack);
  k_wo<<<4000, 256, 0, stream>>>(Wo, Wof);
  k_recur<<<32, 512, 0, stream>>>(H0, Wpack, g_buf, Hn16, out + 131072000LL);
  k_gemm<<<8000, 256, 0, stream>>>(Hn16, Wof, bo, out);
}

// Round 15
// 527.815 us; speedup vs baseline: 1.5861x; 1.3066x over previous
//
#include <hip/hip_runtime.h>
#include <hip/hip_fp16.h>
#include <stdint.h>

#define VV 32000
#define HH 256
#define BB 32
#define TT 128
#define VH 32256  // V + H

typedef _Float16 f16;
typedef _Float16 f16x2 __attribute__((ext_vector_type(2)));
typedef _Float16 f16x8 __attribute__((ext_vector_type(8)));
typedef float f32x16 __attribute__((ext_vector_type(16)));

static __device__ __forceinline__ float dot2f(uint32_t w, uint32_t h, float acc){
  f16x2 a = __builtin_bit_cast(f16x2, w);
  f16x2 b = __builtin_bit_cast(f16x2, h);
#if __has_builtin(__builtin_amdgcn_fdot2)
  return __builtin_amdgcn_fdot2(a, b, acc, false);
#else
  acc = fmaf((float)a[0], (float)b[0], acc);
  acc = fmaf((float)a[1], (float)b[1], acc);
  return acc;
#endif
}

// ---------------- gather: g[t*32+b][o] = W_gate[row][tok] + bias
__global__ void k_gather(const int* __restrict__ X,
                         const float* __restrict__ Wz, const float* __restrict__ bz,
                         const float* __restrict__ Wr, const float* __restrict__ br,
                         const float* __restrict__ Wh, const float* __restrict__ bh,
                         float* __restrict__ g_buf){
  int tb = blockIdx.x;              // t*32 + b
  int t = tb >> 5, b = tb & 31;
  int tok = X[b*TT + t];
  int o = threadIdx.x;              // 0..255
  g_buf[(size_t)tb*768 + o]       = Wz[(size_t)o*VH + tok] + bz[o];
  g_buf[(size_t)tb*768 + 256 + o] = Wr[(size_t)o*VH + tok] + br[o];
  g_buf[(size_t)tb*768 + 512 + o] = Wh[(size_t)o*VH + tok] + bh[o];
}

// ---------------- pack recurrent weights (512-thread layout, round-8 mapping)
__global__ void k_pack(const float* __restrict__ Wz, const float* __restrict__ Wr,
                       const float* __restrict__ Wh, uint32_t* __restrict__ Wpack){
  int idx = blockIdx.x*256 + threadIdx.x;
  if (idx >= 512*192) return;
  int t = idx / 192, rem = idx - t*192;
  int ol = rem >> 4, p = rem & 15;
  int ko = t & 7, no = t >> 3;
  int k = ko*32 + p*2;
  const float* W; int row;
  if (ol < 8){ int o = no*8 + ol; if (o < 256){ W = Wz; row = o; } else { W = Wr; row = o - 256; } }
  else { W = Wh; row = no*4 + (ol - 8); }
  float a = W[(size_t)row*VH + VV + k];
  float c = W[(size_t)row*VH + VV + k + 1];
  f16x2 v; v[0] = (f16)a; v[1] = (f16)c;
  Wpack[idx] = __builtin_bit_cast(uint32_t, v);
}

// ---------------- Wo f32 -> f16 (once)
__global__ void k_wo(const float* __restrict__ Wo, f16* __restrict__ Wof){
  int i = blockIdx.x*256 + threadIdx.x;      // 1,024,000 threads x 8 floats
  const float4* s = (const float4*)Wo + (size_t)i*2;
  float4 f0 = s[0], f1 = s[1];
  f16x8 h;
  h[0]=(f16)f0.x; h[1]=(f16)f0.y; h[2]=(f16)f0.z; h[3]=(f16)f0.w;
  h[4]=(f16)f1.x; h[5]=(f16)f1.y; h[6]=(f16)f1.z; h[7]=(f16)f1.w;
  *(f16x8*)(Wof + (size_t)i*8) = h;
}

// ---------------- recurrence: 32 blocks x 512 threads, waves_per_eu(2,2)  [round-8 champion]
__global__ __launch_bounds__(512)
__attribute__((amdgpu_waves_per_eu(2, 2)))
void k_recur(const float* __restrict__ H0,
             const uint32_t* __restrict__ Wpack,
             const float* __restrict__ g_buf,
             f16* __restrict__ Hn16,
             float* __restrict__ hf_out){
  __shared__ __align__(16) uint32_t hs16[128];   // Hs as f16 pairs
  __shared__ __align__(16) f16 rHs16[256];       // r*Hs as f16
  __shared__ float hs32[256];                    // Hs f32 (state of record)
  __shared__ float z_s[256];

  const int b = blockIdx.x;
  const int tid = threadIdx.x;
  const int ko = tid & 7, no = tid >> 3;   // no in [0,64)

  uint32_t w[12][16];
  {
    const uint4* src = (const uint4*)(Wpack + (size_t)tid*192);
    #pragma unroll
    for (int j=0;j<48;j++){
      uint4 v = src[j];
      int f = j*4;
      w[(f+0)>>4][(f+0)&15] = v.x;
      w[(f+1)>>4][(f+1)&15] = v.y;
      w[(f+2)>>4][(f+2)&15] = v.z;
      w[(f+3)>>4][(f+3)&15] = v.w;
    }
  }

  if (tid < 256) hs32[tid] = H0[b*HH + tid];
  __syncthreads();
  if (tid < 128){
    f16x2 v; v[0] = (f16)hs32[2*tid]; v[1] = (f16)hs32[2*tid+1];
    hs16[tid] = __builtin_bit_cast(uint32_t, v);
  }
  __syncthreads();

  const int gi1 = no*8 + ko;
  const int gi2 = 512 + no*4 + (ko & 3);
  float g1 = g_buf[(size_t)b*768 + gi1];
  float g2 = g_buf[(size_t)b*768 + gi2];
  float g1n = 0.f, g2n = 0.f;

  for (int t = 0; t < TT; t++){
    if (t < TT-1){
      const float* gn = g_buf + (size_t)((t+1)*BB + b)*768;
      g1n = gn[gi1];
      g2n = gn[gi2];
    }

    // ---- phase 1: z (no<32) and r (no>=32), 8 outputs per group
    uint32_t hp[16];
    {
      const uint2* hsp = (const uint2*)hs16;
      #pragma unroll
      for (int j=0;j<8;j++){ uint2 v = hsp[ko*8 + j]; hp[2*j] = v.x; hp[2*j+1] = v.y; }
    }
    float acc[8];
    #pragma unroll
    for (int ol=0;ol<8;ol++) acc[ol] = 0.f;
    #pragma unroll
    for (int p=0;p<16;p++)
      #pragma unroll
      for (int ol=0;ol<8;ol++)
        acc[ol] = dot2f(w[ol][p], hp[p], acc[ol]);
    #pragma unroll
    for (int ol=0;ol<8;ol++){
      float v2 = acc[ol];
      v2 += __shfl_xor(v2, 1);
      v2 += __shfl_xor(v2, 2);
      v2 += __shfl_xor(v2, 4);
      acc[ol] = v2;
    }
    {
      float sel = acc[0];
      #pragma unroll
      for (int ol=1;ol<8;ol++) sel = (ko == ol) ? acc[ol] : sel;
      float pre = sel + g1;
      float s = 1.f / (1.f + __expf(-pre));
      int o = no*8 + ko;
      if (no < 32){
        z_s[o] = s;
      } else {
        int op = o - 256;
        rHs16[op] = (f16)(s * hs32[op]);
      }
    }
    __syncthreads();

    // ---- phase 2: h~ = tanh(gh + (r*Hs)@Wh^T), Hn = z*h~ + (1-z)*Hs
    uint32_t rp[16];
    {
      const uint2* rpp = (const uint2*)rHs16;
      #pragma unroll
      for (int j=0;j<8;j++){ uint2 v = rpp[ko*8 + j]; rp[2*j] = v.x; rp[2*j+1] = v.y; }
    }
    float a2[4];
    #pragma unroll
    for (int oi=0;oi<4;oi++) a2[oi] = 0.f;
    #pragma unroll
    for (int p=0;p<16;p++)
      #pragma unroll
      for (int oi=0;oi<4;oi++)
        a2[oi] = dot2f(w[8+oi][p], rp[p], a2[oi]);
    #pragma unroll
    for (int oi=0;oi<4;oi++){
      float v2 = a2[oi];
      v2 += __shfl_xor(v2, 1);
      v2 += __shfl_xor(v2, 2);
      v2 += __shfl_xor(v2, 4);
      a2[oi] = v2;
    }
    if (ko < 4){
      float sel = a2[0];
      #pragma unroll
      for (int oi=1;oi<4;oi++) sel = (ko == oi) ? a2[oi] : sel;
      int o = no*4 + ko;
      float pre = sel + g2;
      float ax = fabsf(pre);
      float e = __expf(2.f*ax);
      float th = 1.f - 2.f/(e + 1.f);      // tanh(|x|), safe at inf
      th = copysignf(th, pre);
      float z = z_s[o];
      float hn = z*th + (1.f - z)*hs32[o];
      hs32[o] = hn;
      ((f16*)hs16)[o] = (f16)hn;
      Hn16[(size_t)(t*BB + b)*HH + o] = (f16)hn;
      if (t == TT-1) hf_out[b*HH + o] = hn;
    }
    g1 = g1n; g2 = g2n;
    __syncthreads();
  }
}

// ---------------- output GEMM: Y = Hn16 @ Wof^T + bo, mfma 32x32x16 (full-line stores)
__global__ __launch_bounds__(256) void k_gemm(const f16* __restrict__ A, const f16* __restrict__ Wof,
                                              const float* __restrict__ bo, float* __restrict__ Y){
  __shared__ __align__(16) f16 a_lds[128*128];
  __shared__ __align__(16) f16 b_lds[128*128];
  const int wg = (blockIdx.x & 7)*1000 + (blockIdx.x >> 3);   // 8000 = 8 x 1000, bijective
  const int m0 = (wg & 31) * 128;      // m fastest within an XCD chunk -> n-panel reuse in L2
  const int n0 = (wg >> 5) * 128;
  const int tid = threadIdx.x;
  const int lane = tid & 63, wave = tid >> 6;
  const int wm = wave >> 1, wn = wave & 1;   // 2x2 waves, each 64x64 (= 2x2 frags of 32x32)

  f32x16 acc[2][2];
  {
    f32x16 z = {0.f};
    #pragma unroll
    for (int i=0;i<2;i++)
      #pragma unroll
      for (int j=0;j<2;j++) acc[i][j] = z;
  }

  const int srow = tid >> 1, seg = tid & 1;
  #pragma unroll 1
  for (int kt=0; kt<2; kt++){
    const int k0 = kt*128;
    {
      const uint4* asrc = (const uint4*)(A + (size_t)(m0+srow)*256 + k0 + seg*64);
      const uint4* bsrc = (const uint4*)(Wof + (size_t)(n0+srow)*256 + k0 + seg*64);
      #pragma unroll
      for (int j=0;j<8;j++){
        uint4 av = asrc[j];
        int byte = (srow*256 + ((seg*128 + j*16) ^ ((srow&15)<<4)));
        *(uint4*)((char*)a_lds + byte) = av;
        uint4 bv = bsrc[j];
        *(uint4*)((char*)b_lds + byte) = bv;
      }
    }
    __syncthreads();
    #pragma unroll
    for (int kk=0; kk<8; kk++){
      const int kbyte = kk*32 + (lane>>5)*16;   // 8 contiguous f16 at k = kk*16 + (lane>>5)*8
      f16x8 af[2], bf[2];
      #pragma unroll
      for (int mi=0;mi<2;mi++){
        int row = wm*64 + mi*32 + (lane&31);
        int byte = (row*256 + (kbyte ^ ((row&15)<<4)));
        af[mi] = *(const f16x8*)((const char*)a_lds + byte);
      }
      #pragma unroll
      for (int nj=0;nj<2;nj++){
        int nl = wn*64 + nj*32 + (lane&31);
        int byte = (nl*256 + (kbyte ^ ((nl&15)<<4)));
        bf[nj] = *(const f16x8*)((const char*)b_lds + byte);
      }
      #pragma unroll
      for (int mi=0;mi<2;mi++)
        #pragma unroll
        for (int nj=0;nj<2;nj++)
          acc[mi][nj] = __builtin_amdgcn_mfma_f32_32x32x16_f16(af[mi], bf[nj], acc[mi][nj], 0, 0, 0);
    }
    __syncthreads();
  }
  // epilogue: 32x32 C/D map: col = lane&31, row = (reg&3) + 8*(reg>>2) + 4*(lane>>5)
  // -> each dword store covers 2 full 128-B lines (half-wave = 32 consecutive cols)
  #pragma unroll
  for (int nj=0;nj<2;nj++){
    const int col = n0 + wn*64 + nj*32 + (lane & 31);
    const float bov = bo[col];
    #pragma unroll
    for (int mi=0;mi<2;mi++){
      const int rbase = m0 + wm*64 + mi*32 + 4*(lane>>5);
      #pragma unroll
      for (int r=0;r<16;r++){
        int row = rbase + (r&3) + 8*(r>>2);
        Y[(size_t)row*VV + col] = acc[mi][nj][r] + bov;
      }
    }
  }
}

extern "C" void kernel_launch(void* const* d_in, const int* in_sizes, int n_in,
                              void* d_out, int out_size, void* d_ws, size_t ws_size,
                              hipStream_t stream){
  const int*   X  = (const int*)d_in[0];
  const float* H0 = (const float*)d_in[1];
  const float* Wz = (const float*)d_in[2];
  const float* bz = (const float*)d_in[3];
  const float* Wr = (const float*)d_in[4];
  const float* br = (const float*)d_in[5];
  const float* Wh = (const float*)d_in[6];
  const float* bh = (const float*)d_in[7];
  const float* Wo = (const float*)d_in[8];
  const float* bo = (const float*)d_in[9];
  float* out = (float*)d_out;

  char* ws = (char*)d_ws;
  float*    g_buf = (float*)ws;                               // 12,582,912 B
  uint32_t* Wpack = (uint32_t*)(ws + 12582912);               //    393,216 B
  f16*      Hn16  = (f16*)(ws + 12582912 + 393216);           //  2,097,152 B
  f16*      Wof   = (f16*)(ws + 12582912 + 393216 + 2097152); // 16,384,000 B

  k_gather<<<4096, 256, 0, stream>>>(X, Wz, bz, Wr, br, Wh, bh, g_buf);
  k_pack<<<384, 256, 0, stream>>>(Wz, Wr, Wh, Wpack);
  k_wo<<<4000, 256, 0, stream>>>(Wo, Wof);
  k_recur<<<32, 512, 0, stream>>>(H0, Wpack, g_buf, Hn16, out + 131072000LL);
  k_gemm<<<8000, 256, 0, stream>>>(Hn16, Wof, bo, out);
}